// Round 1
// baseline (908.506 us; speedup 1.0000x reference)
//
#include <hip/hip_runtime.h>
#include <hip/hip_bf16.h>

#define BN_INV 0.9999950000375f   // 1/sqrt(1+1e-5)
#define PI_F   3.14159265358979f

// ---------------------------------------------------------------------------
// conv1: x(256,4,3000) -> h1(256,32,3000), BN+ReLU fused
// block 256 = cg(8) x lanes(32); each thread: 4 couts x 8 positions
// ---------------------------------------------------------------------------
__global__ __launch_bounds__(256) void k_conv1(
    const float* __restrict__ x, const float* __restrict__ w,
    const float* __restrict__ cb, const float* __restrict__ bng,
    const float* __restrict__ bnb, float* __restrict__ out)
{
  __shared__ __align__(16) float xs[4][264];
  __shared__ __align__(16) float ws[4][32][8];
  const int tid = threadIdx.x;
  const int b = blockIdx.y;
  const int l0 = blockIdx.x << 8;

  {
    int ci = tid >> 6, p0 = tid & 63;
    const float* xr = x + (b * 4 + ci) * 3000;
    #pragma unroll
    for (int it = 0; it < 5; ++it) {
      int p = p0 + (it << 6);
      if (p < 262) {
        int g = l0 - 3 + p;
        xs[ci][p] = (g >= 0 && g < 3000) ? xr[g] : 0.f;
      }
    }
  }
  for (int e = tid; e < 1024; e += 256) {
    int ci = e >> 8, co = (e >> 3) & 31, k = e & 7;
    ws[ci][co][k] = (k < 7) ? w[co * 28 + ci * 7 + k] : 0.f;
  }
  __syncthreads();

  const int cg = tid >> 5, lg = tid & 31, myl = lg << 3;
  float acc[4][8];
  #pragma unroll
  for (int j = 0; j < 4; ++j)
    #pragma unroll
    for (int p = 0; p < 8; ++p) acc[j][p] = 0.f;

  #pragma unroll
  for (int ci = 0; ci < 4; ++ci) {
    float xv[14];
    {
      const float4* xr4 = reinterpret_cast<const float4*>(&xs[ci][myl]);
      float4 a0 = xr4[0], a1 = xr4[1], a2 = xr4[2];
      float2 a3 = *reinterpret_cast<const float2*>(&xs[ci][myl + 12]);
      xv[0]=a0.x; xv[1]=a0.y; xv[2]=a0.z; xv[3]=a0.w;
      xv[4]=a1.x; xv[5]=a1.y; xv[6]=a1.z; xv[7]=a1.w;
      xv[8]=a2.x; xv[9]=a2.y; xv[10]=a2.z; xv[11]=a2.w;
      xv[12]=a3.x; xv[13]=a3.y;
    }
    #pragma unroll
    for (int j = 0; j < 4; ++j) {
      int co = (j << 3) + cg;
      const float4* wr = reinterpret_cast<const float4*>(&ws[ci][co][0]);
      float4 w0 = wr[0], w1 = wr[1];
      float wv[7] = {w0.x, w0.y, w0.z, w0.w, w1.x, w1.y, w1.z};
      #pragma unroll
      for (int k = 0; k < 7; ++k)
        #pragma unroll
        for (int p = 0; p < 8; ++p)
          acc[j][p] = fmaf(wv[k], xv[p + k], acc[j][p]);
    }
  }

  #pragma unroll
  for (int j = 0; j < 4; ++j) {
    int co = (j << 3) + cg;
    float sc = bng[co] * BN_INV;
    float sh = fmaf(cb[co], sc, bnb[co]);
    float r[8];
    #pragma unroll
    for (int p = 0; p < 8; ++p) r[p] = fmaxf(fmaf(acc[j][p], sc, sh), 0.f);
    int pos = l0 + myl;
    float* orow = out + ((b << 5) + co) * 3000 + pos;
    if (pos + 7 < 3000) {
      *reinterpret_cast<float4*>(orow)     = make_float4(r[0], r[1], r[2], r[3]);
      *reinterpret_cast<float4*>(orow + 4) = make_float4(r[4], r[5], r[6], r[7]);
    } else {
      #pragma unroll
      for (int p = 0; p < 8; ++p) if (pos + p < 3000) orow[p] = r[p];
    }
  }
}

// ---------------------------------------------------------------------------
// conv2: h1(256,32,3000) -> BN+ReLU+maxpool4 -> h2p(256,64,750)
// block 256 = cg(16) x lg(16); thread: 4 couts (j*16+cg) x 8 positions
// ---------------------------------------------------------------------------
__global__ __launch_bounds__(256) void k_conv2(
    const float* __restrict__ in, const float* __restrict__ w,
    const float* __restrict__ cb, const float* __restrict__ bng,
    const float* __restrict__ bnb, float* __restrict__ out)
{
  __shared__ __align__(16) float xs[32][136];
  __shared__ __align__(16) float ws[8][64][8];
  const int tid = threadIdx.x;
  const int b = blockIdx.y;
  const int l0 = blockIdx.x << 7;

  {
    int c0 = tid >> 5, p0 = tid & 31;
    #pragma unroll
    for (int pass = 0; pass < 4; ++pass) {
      int ci = (pass << 3) + c0;
      const float* xr = in + (b * 32 + ci) * 3000;
      #pragma unroll
      for (int it = 0; it < 5; ++it) {
        int p = p0 + (it << 5);
        if (p < 134) {
          int g = l0 - 3 + p;
          xs[ci][p] = (g >= 0 && g < 3000) ? xr[g] : 0.f;
        }
      }
    }
  }

  const int cg = tid >> 4, lg = tid & 15, myl = lg << 3;
  float acc[4][8];
  #pragma unroll
  for (int j = 0; j < 4; ++j)
    #pragma unroll
    for (int p = 0; p < 8; ++p) acc[j][p] = 0.f;

  for (int ch = 0; ch < 4; ++ch) {
    __syncthreads();
    #pragma unroll
    for (int e0 = 0; e0 < 16; ++e0) {
      int e = (e0 << 8) + tid;
      int ci_l = e >> 9, co = (e >> 3) & 63, k = e & 7;
      ws[ci_l][co][k] = (k < 7) ? w[co * 224 + ((ch << 3) + ci_l) * 7 + k] : 0.f;
    }
    __syncthreads();
    #pragma unroll
    for (int ci_l = 0; ci_l < 8; ++ci_l) {
      int ci = (ch << 3) + ci_l;
      float xv[14];
      {
        const float4* xr4 = reinterpret_cast<const float4*>(&xs[ci][myl]);
        float4 a0 = xr4[0], a1 = xr4[1], a2 = xr4[2];
        float2 a3 = *reinterpret_cast<const float2*>(&xs[ci][myl + 12]);
        xv[0]=a0.x; xv[1]=a0.y; xv[2]=a0.z; xv[3]=a0.w;
        xv[4]=a1.x; xv[5]=a1.y; xv[6]=a1.z; xv[7]=a1.w;
        xv[8]=a2.x; xv[9]=a2.y; xv[10]=a2.z; xv[11]=a2.w;
        xv[12]=a3.x; xv[13]=a3.y;
      }
      #pragma unroll
      for (int j = 0; j < 4; ++j) {
        int co = (j << 4) + cg;
        const float4* wr = reinterpret_cast<const float4*>(&ws[ci_l][co][0]);
        float4 w0 = wr[0], w1 = wr[1];
        float wv[7] = {w0.x, w0.y, w0.z, w0.w, w1.x, w1.y, w1.z};
        #pragma unroll
        for (int k = 0; k < 7; ++k)
          #pragma unroll
          for (int p = 0; p < 8; ++p)
            acc[j][p] = fmaf(wv[k], xv[p + k], acc[j][p]);
      }
    }
  }

  #pragma unroll
  for (int j = 0; j < 4; ++j) {
    int co = (j << 4) + cg;
    float sc = bng[co] * BN_INV;
    float sh = fmaf(cb[co], sc, bnb[co]);
    float r[8];
    #pragma unroll
    for (int p = 0; p < 8; ++p) r[p] = fmaxf(fmaf(acc[j][p], sc, sh), 0.f);
    float m0 = fmaxf(fmaxf(r[0], r[1]), fmaxf(r[2], r[3]));
    float m1 = fmaxf(fmaxf(r[4], r[5]), fmaxf(r[6], r[7]));
    int lp0 = (l0 + myl) >> 2;
    float* orow = out + ((b << 6) + co) * 750;
    if (lp0 + 1 < 750) {
      *reinterpret_cast<float2*>(orow + lp0) = make_float2(m0, m1);
    } else if (lp0 < 750) {
      orow[lp0] = m0;
    }
  }
}

// ---------------------------------------------------------------------------
// conv3: h2p(256,64,750) -> BN+ReLU+maxpool4 -> h3p(256,128,187)
// block 256 = cg(32) x lg(8); thread: 4 couts (j*32+cg) x 16 positions
// ---------------------------------------------------------------------------
__global__ __launch_bounds__(256) void k_conv3(
    const float* __restrict__ in, const float* __restrict__ w,
    const float* __restrict__ cb, const float* __restrict__ bng,
    const float* __restrict__ bnb, float* __restrict__ out)
{
  __shared__ __align__(16) float xs[64][136];
  __shared__ __align__(16) float ws[4][128][8];
  const int tid = threadIdx.x;
  const int b = blockIdx.y;
  const int l0 = blockIdx.x << 7;

  {
    int c0 = tid >> 5, p0 = tid & 31;
    #pragma unroll
    for (int pass = 0; pass < 8; ++pass) {
      int ci = (pass << 3) + c0;
      const float* xr = in + (b * 64 + ci) * 750;
      #pragma unroll
      for (int it = 0; it < 5; ++it) {
        int p = p0 + (it << 5);
        if (p < 134) {
          int g = l0 - 3 + p;
          xs[ci][p] = (g >= 0 && g < 750) ? xr[g] : 0.f;
        }
      }
    }
  }

  const int cg = tid >> 3, lg = tid & 7, myl = lg << 4;
  float acc[4][16];
  #pragma unroll
  for (int j = 0; j < 4; ++j)
    #pragma unroll
    for (int p = 0; p < 16; ++p) acc[j][p] = 0.f;

  for (int ch = 0; ch < 16; ++ch) {
    __syncthreads();
    #pragma unroll
    for (int e0 = 0; e0 < 16; ++e0) {
      int e = (e0 << 8) + tid;
      int ci_l = e >> 10, co = (e >> 3) & 127, k = e & 7;
      ws[ci_l][co][k] = (k < 7) ? w[co * 448 + ((ch << 2) + ci_l) * 7 + k] : 0.f;
    }
    __syncthreads();
    #pragma unroll
    for (int ci_l = 0; ci_l < 4; ++ci_l) {
      int ci = (ch << 2) + ci_l;
      float xv[22];
      {
        const float4* xr4 = reinterpret_cast<const float4*>(&xs[ci][myl]);
        float4 a0 = xr4[0], a1 = xr4[1], a2 = xr4[2], a3 = xr4[3], a4 = xr4[4];
        float2 a5 = *reinterpret_cast<const float2*>(&xs[ci][myl + 20]);
        xv[0]=a0.x; xv[1]=a0.y; xv[2]=a0.z; xv[3]=a0.w;
        xv[4]=a1.x; xv[5]=a1.y; xv[6]=a1.z; xv[7]=a1.w;
        xv[8]=a2.x; xv[9]=a2.y; xv[10]=a2.z; xv[11]=a2.w;
        xv[12]=a3.x; xv[13]=a3.y; xv[14]=a3.z; xv[15]=a3.w;
        xv[16]=a4.x; xv[17]=a4.y; xv[18]=a4.z; xv[19]=a4.w;
        xv[20]=a5.x; xv[21]=a5.y;
      }
      #pragma unroll
      for (int j = 0; j < 4; ++j) {
        int co = (j << 5) + cg;
        const float4* wr = reinterpret_cast<const float4*>(&ws[ci_l][co][0]);
        float4 w0 = wr[0], w1 = wr[1];
        float wv[7] = {w0.x, w0.y, w0.z, w0.w, w1.x, w1.y, w1.z};
        #pragma unroll
        for (int k = 0; k < 7; ++k)
          #pragma unroll
          for (int p = 0; p < 16; ++p)
            acc[j][p] = fmaf(wv[k], xv[p + k], acc[j][p]);
      }
    }
  }

  #pragma unroll
  for (int j = 0; j < 4; ++j) {
    int co = (j << 5) + cg;
    float sc = bng[co] * BN_INV;
    float sh = fmaf(cb[co], sc, bnb[co]);
    float r[16];
    #pragma unroll
    for (int p = 0; p < 16; ++p) r[p] = fmaxf(fmaf(acc[j][p], sc, sh), 0.f);
    int lp0 = (l0 + myl) >> 2;
    float* orow = out + ((b << 7) + co) * 187;
    #pragma unroll
    for (int q = 0; q < 4; ++q) {
      float m = fmaxf(fmaxf(r[4*q], r[4*q+1]), fmaxf(r[4*q+2], r[4*q+3]));
      if (lp0 + q < 187) orow[lp0 + q] = m;
    }
  }
}

// ---------------------------------------------------------------------------
// conv4: h3p(256,128,187) -> BN+ReLU -> mean over L -> h4(256,128)
// grid (2,256): block handles 64 couts, all 128 ci, all positions
// block 256 = cg(16) x lg(16); thread: 4 couts x 12 positions (covers 192)
// ---------------------------------------------------------------------------
__global__ __launch_bounds__(256) void k_conv4(
    const float* __restrict__ in, const float* __restrict__ w,
    const float* __restrict__ cb, const float* __restrict__ bng,
    const float* __restrict__ bnb, float* __restrict__ h4)
{
  __shared__ __align__(16) float xs[8][200];
  __shared__ __align__(16) float ws[8][64][8];
  __shared__ float red[256][4];
  const int tid = threadIdx.x;
  const int b = blockIdx.y;
  const int co_base = blockIdx.x << 6;

  const int cg = tid >> 4, lg = tid & 15, myl = lg * 12;
  float acc[4][12];
  #pragma unroll
  for (int j = 0; j < 4; ++j)
    #pragma unroll
    for (int p = 0; p < 12; ++p) acc[j][p] = 0.f;

  for (int ch = 0; ch < 16; ++ch) {
    __syncthreads();
    {
      int c0 = tid >> 5, p0 = tid & 31;
      int ci = (ch << 3) + c0;
      const float* xr = in + (b * 128 + ci) * 187;
      #pragma unroll
      for (int it = 0; it < 7; ++it) {
        int p = p0 + (it << 5);
        if (p < 200) {
          int g = p - 3;
          xs[c0][p] = (g >= 0 && g < 187) ? xr[g] : 0.f;
        }
      }
    }
    #pragma unroll
    for (int e0 = 0; e0 < 16; ++e0) {
      int e = (e0 << 8) + tid;
      int ci_l = e >> 9, co_l = (e >> 3) & 63, k = e & 7;
      ws[ci_l][co_l][k] =
          (k < 7) ? w[(co_base + co_l) * 896 + ((ch << 3) + ci_l) * 7 + k] : 0.f;
    }
    __syncthreads();
    #pragma unroll
    for (int ci_l = 0; ci_l < 8; ++ci_l) {
      float xv[18];
      {
        const float4* xr4 = reinterpret_cast<const float4*>(&xs[ci_l][myl]);
        float4 a0 = xr4[0], a1 = xr4[1], a2 = xr4[2], a3 = xr4[3];
        float2 a4 = *reinterpret_cast<const float2*>(&xs[ci_l][myl + 16]);
        xv[0]=a0.x; xv[1]=a0.y; xv[2]=a0.z; xv[3]=a0.w;
        xv[4]=a1.x; xv[5]=a1.y; xv[6]=a1.z; xv[7]=a1.w;
        xv[8]=a2.x; xv[9]=a2.y; xv[10]=a2.z; xv[11]=a2.w;
        xv[12]=a3.x; xv[13]=a3.y; xv[14]=a3.z; xv[15]=a3.w;
        xv[16]=a4.x; xv[17]=a4.y;
      }
      #pragma unroll
      for (int j = 0; j < 4; ++j) {
        int co_l = (j << 4) + cg;
        const float4* wr = reinterpret_cast<const float4*>(&ws[ci_l][co_l][0]);
        float4 w0 = wr[0], w1 = wr[1];
        float wv[7] = {w0.x, w0.y, w0.z, w0.w, w1.x, w1.y, w1.z};
        #pragma unroll
        for (int k = 0; k < 7; ++k)
          #pragma unroll
          for (int p = 0; p < 12; ++p)
            acc[j][p] = fmaf(wv[k], xv[p + k], acc[j][p]);
      }
    }
  }

  float sum[4];
  #pragma unroll
  for (int j = 0; j < 4; ++j) {
    int co = co_base + (j << 4) + cg;
    float sc = bng[co] * BN_INV;
    float sh = fmaf(cb[co], sc, bnb[co]);
    float s = 0.f;
    #pragma unroll
    for (int p = 0; p < 12; ++p) {
      int pos = myl + p;
      float v = fmaxf(fmaf(acc[j][p], sc, sh), 0.f);
      if (pos < 187) s += v;
    }
    sum[j] = s;
  }
  #pragma unroll
  for (int j = 0; j < 4; ++j) red[tid][j] = sum[j];
  __syncthreads();
  if (lg == 0) {
    #pragma unroll
    for (int j = 0; j < 4; ++j) {
      float s = 0.f;
      for (int t = 0; t < 16; ++t) s += red[(cg << 4) + t][j];
      h4[b * 128 + co_base + (j << 4) + cg] = s * (1.0f / 187.0f);
    }
  }
}

// ---------------------------------------------------------------------------
// head: h4(256,128) -> fc+relu -> ang -> pi*tanh -> 8-qubit sim -> h1 -> h2
// one block (256 threads) per batch element; state in LDS
// ---------------------------------------------------------------------------
__global__ __launch_bounds__(256) void k_head(
    const float* __restrict__ h4, const float* __restrict__ fc_w,
    const float* __restrict__ fc_b, const float* __restrict__ ang_w,
    const float* __restrict__ ang_b, const float* __restrict__ qw,
    const float* __restrict__ h1_w, const float* __restrict__ h1_b,
    const float* __restrict__ h2_w, const float* __restrict__ h2_b,
    float* __restrict__ out)
{
  __shared__ float hvec[128], fvec[128];
  __shared__ float rc[8], rs[8];
  __shared__ float rotm[16][8];
  __shared__ float2 st[256];
  __shared__ float parr[256];
  __shared__ float zv[8];
  __shared__ float hh[64];

  const int tid = threadIdx.x;
  const int b = blockIdx.x;

  if (tid < 128) hvec[tid] = h4[b * 128 + tid];
  __syncthreads();

  if (tid < 128) {
    float a = fc_b[tid];
    const float* wr = fc_w + tid * 128;
    for (int k = 0; k < 128; ++k) a = fmaf(hvec[k], wr[k], a);
    fvec[tid] = fmaxf(a, 0.f);
  }
  __syncthreads();

  if (tid < 8) {
    float a = ang_b[tid];
    const float* wr = ang_w + tid * 128;
    for (int k = 0; k < 128; ++k) a = fmaf(fvec[k], wr[k], a);
    float ang = PI_F * tanhf(a);
    rc[tid] = cosf(0.5f * ang);
    rs[tid] = sinf(0.5f * ang);
  }
  if (tid >= 32 && tid < 48) {
    int g = tid - 32;
    float phi = qw[g * 3 + 0], th = qw[g * 3 + 1], om = qw[g * 3 + 2];
    float cm = cosf(0.5f * th), sm = sinf(0.5f * th);
    float a = 0.5f * (phi + om), bb = 0.5f * (phi - om);
    float ca = cosf(a), sa = sinf(a), cbb = cosf(bb), sbb = sinf(bb);
    rotm[g][0] =  cm * ca;  rotm[g][1] = -cm * sa;   // m00
    rotm[g][2] = -sm * cbb; rotm[g][3] = -sm * sbb;  // m01
    rotm[g][4] =  sm * cbb; rotm[g][5] = -sm * sbb;  // m10
    rotm[g][6] =  cm * ca;  rotm[g][7] =  cm * sa;   // m11
  }
  st[tid] = make_float2(tid == 0 ? 1.f : 0.f, 0.f);
  __syncthreads();

  // AngleEmbedding: RY on each wire (wire 0 = MSB)
  for (int w = 0; w < 8; ++w) {
    if (tid < 128) {
      int bit = 7 - w;
      int i0 = ((tid >> bit) << (bit + 1)) | (tid & ((1 << bit) - 1));
      int i1 = i0 | (1 << bit);
      float c = rc[w], s = rs[w];
      float2 a0 = st[i0], a1 = st[i1];
      st[i0] = make_float2(c * a0.x - s * a1.x, c * a0.y - s * a1.y);
      st[i1] = make_float2(s * a0.x + c * a1.x, s * a0.y + c * a1.y);
    }
    __syncthreads();
  }

  // StronglyEntanglingLayers
  for (int l = 0; l < 2; ++l) {
    for (int w = 0; w < 8; ++w) {
      if (tid < 128) {
        int g = l * 8 + w;
        int bit = 7 - w;
        int i0 = ((tid >> bit) << (bit + 1)) | (tid & ((1 << bit) - 1));
        int i1 = i0 | (1 << bit);
        float2 a0 = st[i0], a1 = st[i1];
        float m00x = rotm[g][0], m00y = rotm[g][1];
        float m01x = rotm[g][2], m01y = rotm[g][3];
        float m10x = rotm[g][4], m10y = rotm[g][5];
        float m11x = rotm[g][6], m11y = rotm[g][7];
        float2 n0, n1;
        n0.x = m00x * a0.x - m00y * a0.y + m01x * a1.x - m01y * a1.y;
        n0.y = m00x * a0.y + m00y * a0.x + m01x * a1.y + m01y * a1.x;
        n1.x = m10x * a0.x - m10y * a0.y + m11x * a1.x - m11y * a1.y;
        n1.y = m10x * a0.y + m10y * a0.x + m11x * a1.y + m11y * a1.x;
        st[i0] = n0;
        st[i1] = n1;
      }
      __syncthreads();
    }
    int r = (l % 7) + 1;
    for (int i = 0; i < 8; ++i) {
      int c = i, t = (i + r) & 7;
      int cmask = 1 << (7 - c), tmask = 1 << (7 - t);
      int src = (tid & cmask) ? (tid ^ tmask) : tid;
      float2 v = st[src];
      __syncthreads();
      st[tid] = v;
      __syncthreads();
    }
  }

  parr[tid] = st[tid].x * st[tid].x + st[tid].y * st[tid].y;
  __syncthreads();
  if (tid < 8) {
    int bit = 7 - tid;
    float z = 0.f;
    for (int i = 0; i < 256; ++i)
      z += (i & (1 << bit)) ? -parr[i] : parr[i];
    zv[tid] = z;
  }
  __syncthreads();
  if (tid < 64) {
    float a = h1_b[tid];
    #pragma unroll
    for (int k = 0; k < 8; ++k) a = fmaf(zv[k], h1_w[tid * 8 + k], a);
    hh[tid] = fmaxf(a, 0.f);
  }
  __syncthreads();
  if (tid < 5) {
    float a = h2_b[tid];
    for (int j = 0; j < 64; ++j) a = fmaf(hh[j], h2_w[tid * 64 + j], a);
    out[b * 5 + tid] = a;
  }
}

// ---------------------------------------------------------------------------
extern "C" void kernel_launch(void* const* d_in, const int* in_sizes, int n_in,
                              void* d_out, int out_size, void* d_ws, size_t ws_size,
                              hipStream_t stream) {
  (void)in_sizes; (void)n_in; (void)out_size; (void)ws_size;
  const float* x    = (const float*)d_in[0];
  const float* c1w  = (const float*)d_in[1];
  const float* c1b  = (const float*)d_in[2];
  const float* b1g  = (const float*)d_in[3];
  const float* b1b  = (const float*)d_in[4];
  const float* c2w  = (const float*)d_in[5];
  const float* c2b  = (const float*)d_in[6];
  const float* b2g  = (const float*)d_in[7];
  const float* b2b  = (const float*)d_in[8];
  const float* c3w  = (const float*)d_in[9];
  const float* c3b  = (const float*)d_in[10];
  const float* b3g  = (const float*)d_in[11];
  const float* b3b  = (const float*)d_in[12];
  const float* c4w  = (const float*)d_in[13];
  const float* c4b  = (const float*)d_in[14];
  const float* b4g  = (const float*)d_in[15];
  const float* b4b  = (const float*)d_in[16];
  const float* fcw  = (const float*)d_in[17];
  const float* fcb  = (const float*)d_in[18];
  const float* angw = (const float*)d_in[19];
  const float* angb = (const float*)d_in[20];
  const float* qw   = (const float*)d_in[21];
  const float* h1w  = (const float*)d_in[22];
  const float* h1b  = (const float*)d_in[23];
  const float* h2w  = (const float*)d_in[24];
  const float* h2b  = (const float*)d_in[25];

  float* wsf = (float*)d_ws;
  float* h1  = wsf;                         // 256*32*3000 = 24,576,000 floats
  float* h2p = wsf + 24576000;              // 256*64*750  = 12,288,000 floats
  float* h3p = wsf;                         // reuse h1 region (dead after conv2)
  float* h4  = wsf + 24576000 + 12288000;   // 256*128 = 32,768 floats

  k_conv1<<<dim3(12, 256), 256, 0, stream>>>(x,   c1w, c1b, b1g, b1b, h1);
  k_conv2<<<dim3(24, 256), 256, 0, stream>>>(h1,  c2w, c2b, b2g, b2b, h2p);
  k_conv3<<<dim3(6, 256),  256, 0, stream>>>(h2p, c3w, c3b, b3g, b3b, h3p);
  k_conv4<<<dim3(2, 256),  256, 0, stream>>>(h3p, c4w, c4b, b4g, b4b, h4);
  k_head<<<dim3(256), 256, 0, stream>>>(h4, fcw, fcb, angw, angb, qw,
                                        h1w, h1b, h2w, h2b, (float*)d_out);
}

// Round 2
// 251.400 us; speedup vs baseline: 3.6138x; 3.6138x over previous
//
#include <hip/hip_runtime.h>
#include <hip/hip_bf16.h>

#define BN_INV 0.9999950000375f   // 1/sqrt(1+1e-5)
#define PI_F   3.14159265358979f

typedef __attribute__((ext_vector_type(8))) short s16x8;
typedef __attribute__((ext_vector_type(4))) float f32x4;
typedef __attribute__((ext_vector_type(4))) unsigned short u16x4;

__device__ inline unsigned short f2bf(float f) {
  union { float f; unsigned u; } v; v.f = f;
  unsigned r = v.u + 0x7fffu + ((v.u >> 16) & 1u);
  return (unsigned short)(r >> 16);
}

// ---------------------------------------------------------------------------
// pack: fp32 conv weights -> bf16 packed [co][k], k = kk*Ci_pad + ci
//   w1p: [32][64]  (Ci pad 4->8, kk pad 7->8)
//   w2p: [64][224] (k = kk*32+ci)   w3p: [128][448]   w4p: [128][896]
// also zero h4 (conv4 accumulates with atomics)
// ---------------------------------------------------------------------------
__global__ __launch_bounds__(256) void k_pack(
    const float* __restrict__ w1, const float* __restrict__ w2,
    const float* __restrict__ w3, const float* __restrict__ w4,
    unsigned short* __restrict__ w1p, unsigned short* __restrict__ w2p,
    unsigned short* __restrict__ w3p, unsigned short* __restrict__ w4p,
    float* __restrict__ h4)
{
  int e = blockIdx.x * 256 + threadIdx.x;
  if (e < 2048) {
    int co = e >> 6, k = e & 63, kk = k >> 3, ci = k & 7;
    w1p[e] = (ci < 4 && kk < 7) ? f2bf(w1[co * 28 + ci * 7 + kk]) : (unsigned short)0;
  } else if (e < 16384) {
    int t = e - 2048; int co = t / 224, k = t % 224, kk = k >> 5, ci = k & 31;
    w2p[t] = f2bf(w2[co * 224 + ci * 7 + kk]);
  } else if (e < 73728) {
    int t = e - 16384; int co = t / 448, k = t % 448, kk = k >> 6, ci = k & 63;
    w3p[t] = f2bf(w3[co * 448 + ci * 7 + kk]);
  } else if (e < 188416) {
    int t = e - 73728; int co = t / 896, k = t % 896, kk = k >> 7, ci = k & 127;
    w4p[t] = f2bf(w4[co * 896 + ci * 7 + kk]);
  } else if (e < 221184) {
    h4[e - 188416] = 0.f;
  }
}

// ---------------------------------------------------------------------------
// conv1 MFMA: x fp32 (256,4,3000) -> h1t bf16 [b][3000][32], BN+ReLU
// block: co32 x pos512; 4 waves, wave = co32(2m) x pos128(8n); K=64 (2 ksteps)
// xT rows 16B (8 ci, 4 zero-pad) -> B-frag = contiguous 16B, no swizzle needed
// ---------------------------------------------------------------------------
__global__ __launch_bounds__(256) void k_conv1(
    const float* __restrict__ x, const unsigned short* __restrict__ w1p,
    const float* __restrict__ cb, const float* __restrict__ bng,
    const float* __restrict__ bnb, unsigned short* __restrict__ h1t)
{
  __shared__ __align__(16) char lds[520 * 16 + 4096 + 256];
  float* scs = (float*)(lds + 520 * 16 + 4096);
  const int tid = threadIdx.x;
  const int b = blockIdx.y;
  const int l0 = blockIdx.x * 512;

  for (int r = tid; r < 519; r += 256) {
    int gr = l0 + r - 3;
    s16x8 v;
    if (gr >= 0 && gr < 3000) {
      const float* xr = x + b * 4 * 3000 + gr;
      v[0] = (short)f2bf(xr[0]);
      v[1] = (short)f2bf(xr[3000]);
      v[2] = (short)f2bf(xr[6000]);
      v[3] = (short)f2bf(xr[9000]);
      v[4] = 0; v[5] = 0; v[6] = 0; v[7] = 0;
    } else {
      for (int i = 0; i < 8; ++i) v[i] = 0;
    }
    *(s16x8*)(lds + r * 16) = v;
  }
  {  // weights: 32co x 8 chunks = 256 threads exactly
    int co = tid >> 3, c = tid & 7;
    s16x8 v = *(const s16x8*)(w1p + co * 64 + c * 8);
    *(s16x8*)(lds + 8320 + ((co * 128 + c * 16) ^ ((co & 7) << 4))) = v;
  }
  if (tid < 32) {
    float sc = bng[tid] * BN_INV;
    scs[tid * 2] = sc;
    scs[tid * 2 + 1] = fmaf(cb[tid], sc, bnb[tid]);
  }
  __syncthreads();

  const int w = tid >> 6, l = tid & 63, lr = l & 15, g = l >> 4;
  const int wp = w * 128;
  f32x4 acc[2][8];
  for (int m = 0; m < 2; ++m)
    for (int n = 0; n < 8; ++n)
      for (int i = 0; i < 4; ++i) acc[m][n][i] = 0.f;

  #pragma unroll
  for (int s = 0; s < 2; ++s) {
    s16x8 a[2], bf[8];
    #pragma unroll
    for (int m = 0; m < 2; ++m) {
      int co = m * 16 + lr;
      a[m] = *(const s16x8*)(lds + 8320 + ((co * 128 + s * 64 + g * 16) ^ ((co & 7) << 4)));
    }
    #pragma unroll
    for (int n = 0; n < 8; ++n) {
      int row = wp + n * 16 + lr + s * 4 + g;
      bf[n] = *(const s16x8*)(lds + row * 16);
    }
    #pragma unroll
    for (int m = 0; m < 2; ++m)
      #pragma unroll
      for (int n = 0; n < 8; ++n)
        acc[m][n] = __builtin_amdgcn_mfma_f32_16x16x32_bf16(a[m], bf[n], acc[m][n], 0, 0, 0);
  }

  #pragma unroll
  for (int m = 0; m < 2; ++m) {
    int co0 = m * 16 + g * 4;
    float sc[4], sh[4];
    #pragma unroll
    for (int j = 0; j < 4; ++j) { sc[j] = scs[(co0 + j) * 2]; sh[j] = scs[(co0 + j) * 2 + 1]; }
    #pragma unroll
    for (int n = 0; n < 8; ++n) {
      int gp = l0 + wp + n * 16 + lr;
      if (gp < 3000) {
        u16x4 o;
        #pragma unroll
        for (int j = 0; j < 4; ++j)
          o[j] = f2bf(fmaxf(fmaf(acc[m][n][j], sc[j], sh[j]), 0.f));
        *(u16x4*)(h1t + (b * 3000 + gp) * 32 + co0) = o;
      }
    }
  }
}

// ---------------------------------------------------------------------------
// conv2 MFMA: h1t bf16 -> BN+ReLU+pool4 -> h2pt bf16 [b][750][64]
// block: co64 x pos256; wave = co64(4m) x pos64(4n); K=224 (7 ksteps, kk=s)
// ---------------------------------------------------------------------------
__global__ __launch_bounds__(256) void k_conv2(
    const unsigned short* __restrict__ h1t, const unsigned short* __restrict__ w2p,
    const float* __restrict__ cb, const float* __restrict__ bng,
    const float* __restrict__ bnb, unsigned short* __restrict__ h2pt)
{
  __shared__ __align__(16) char lds[264 * 64 + 28672 + 512];
  float* scs = (float*)(lds + 264 * 64 + 28672);
  const int tid = threadIdx.x, b = blockIdx.y;
  const int l0 = blockIdx.x * 256;

  for (int e = tid; e < 1048; e += 256) {  // 262 rows x 4 chunks
    int r = e >> 2, c = e & 3;
    int gr = l0 + r - 3;
    s16x8 v;
    if (gr >= 0 && gr < 3000) v = *(const s16x8*)(h1t + (b * 3000 + gr) * 32 + c * 8);
    else for (int i = 0; i < 8; ++i) v[i] = 0;
    *(s16x8*)(lds + ((r * 64 + c * 16) ^ ((r & 7) << 4))) = v;
  }
  for (int e = tid; e < 1792; e += 256) {  // 64co x 28 chunks
    int co = e / 28, c = e % 28;
    s16x8 v = *(const s16x8*)(w2p + co * 224 + c * 8);
    *(s16x8*)(lds + 16896 + ((co * 448 + c * 16) ^ ((co & 7) << 4))) = v;
  }
  if (tid < 64) {
    float sc = bng[tid] * BN_INV;
    scs[tid * 2] = sc;
    scs[tid * 2 + 1] = fmaf(cb[tid], sc, bnb[tid]);
  }
  __syncthreads();

  const int w = tid >> 6, l = tid & 63, lr = l & 15, g = l >> 4;
  const int wp = w * 64;
  f32x4 acc[4][4];
  for (int m = 0; m < 4; ++m)
    for (int n = 0; n < 4; ++n)
      for (int i = 0; i < 4; ++i) acc[m][n][i] = 0.f;

  #pragma unroll
  for (int s = 0; s < 7; ++s) {
    s16x8 a[4], bf[4];
    #pragma unroll
    for (int m = 0; m < 4; ++m) {
      int co = m * 16 + lr;
      a[m] = *(const s16x8*)(lds + 16896 + ((co * 448 + s * 64 + g * 16) ^ ((co & 7) << 4)));
    }
    #pragma unroll
    for (int n = 0; n < 4; ++n) {
      int row = wp + n * 16 + lr + s;
      bf[n] = *(const s16x8*)(lds + ((row * 64 + g * 16) ^ ((row & 7) << 4)));
    }
    #pragma unroll
    for (int m = 0; m < 4; ++m)
      #pragma unroll
      for (int n = 0; n < 4; ++n)
        acc[m][n] = __builtin_amdgcn_mfma_f32_16x16x32_bf16(a[m], bf[n], acc[m][n], 0, 0, 0);
  }

  #pragma unroll
  for (int m = 0; m < 4; ++m) {
    int co0 = m * 16 + g * 4;
    float sc[4], sh[4];
    #pragma unroll
    for (int j = 0; j < 4; ++j) { sc[j] = scs[(co0 + j) * 2]; sh[j] = scs[(co0 + j) * 2 + 1]; }
    #pragma unroll
    for (int n = 0; n < 4; ++n) {
      u16x4 o;
      #pragma unroll
      for (int j = 0; j < 4; ++j) {
        float t = fmaxf(fmaf(acc[m][n][j], sc[j], sh[j]), 0.f);
        float t1 = fmaxf(t, __shfl_xor(t, 1));
        float t2 = fmaxf(t1, __shfl_xor(t1, 2));
        o[j] = f2bf(t2);
      }
      int pp = (l0 + wp + n * 16 + lr) >> 2;
      if ((l & 3) == 0 && pp < 750)
        *(u16x4*)(h2pt + (b * 750 + pp) * 64 + co0) = o;
    }
  }
}

// ---------------------------------------------------------------------------
// conv3 MFMA: h2pt -> BN+ReLU+pool4 -> h3pt bf16 [b][187][128]
// block: co64(half) x pos128; wave = co64(4m) x pos32(2n); K=448, 2 w-chunks
// ---------------------------------------------------------------------------
__global__ __launch_bounds__(256) void k_conv3(
    const unsigned short* __restrict__ h2pt, const unsigned short* __restrict__ w3p,
    const float* __restrict__ cb, const float* __restrict__ bng,
    const float* __restrict__ bnb, unsigned short* __restrict__ h3pt)
{
  __shared__ __align__(16) char lds[136 * 128 + 28672 + 512];
  float* scs = (float*)(lds + 136 * 128 + 28672);
  const int tid = threadIdx.x, b = blockIdx.y;
  const int tile = blockIdx.x >> 1, ch = blockIdx.x & 1;
  const int l0 = tile * 128, cg0 = ch * 64;

  for (int e = tid; e < 1072; e += 256) {  // 134 rows x 8 chunks
    int r = e >> 3, c = e & 7;
    int gr = l0 + r - 3;
    s16x8 v;
    if (gr >= 0 && gr < 750) v = *(const s16x8*)(h2pt + (b * 750 + gr) * 64 + c * 8);
    else for (int i = 0; i < 8; ++i) v[i] = 0;
    *(s16x8*)(lds + ((r * 128 + c * 16) ^ ((r & 7) << 4))) = v;
  }
  if (tid < 64) {
    int co = cg0 + tid;
    float sc = bng[co] * BN_INV;
    scs[tid * 2] = sc;
    scs[tid * 2 + 1] = fmaf(cb[co], sc, bnb[co]);
  }

  const int w = tid >> 6, l = tid & 63, lr = l & 15, g = l >> 4;
  const int wp = w * 32;
  f32x4 acc[4][2];
  for (int m = 0; m < 4; ++m)
    for (int n = 0; n < 2; ++n)
      for (int i = 0; i < 4; ++i) acc[m][n][i] = 0.f;

  for (int chunk = 0; chunk < 2; ++chunk) {
    __syncthreads();
    for (int e = tid; e < 1792; e += 256) {  // 64co x 28 chunks (K-half)
      int co = e / 28, c = e % 28;
      s16x8 v = *(const s16x8*)(w3p + (cg0 + co) * 448 + chunk * 224 + c * 8);
      *(s16x8*)(lds + 17408 + ((co * 448 + c * 16) ^ ((co & 7) << 4))) = v;
    }
    __syncthreads();
    #pragma unroll
    for (int sl = 0; sl < 7; ++sl) {
      int k0 = chunk * 224 + sl * 32;
      int kk = k0 >> 6, cib = k0 & 63;
      s16x8 a[4], bf[2];
      #pragma unroll
      for (int m = 0; m < 4; ++m) {
        int co = m * 16 + lr;
        a[m] = *(const s16x8*)(lds + 17408 + ((co * 448 + sl * 64 + g * 16) ^ ((co & 7) << 4)));
      }
      #pragma unroll
      for (int n = 0; n < 2; ++n) {
        int row = wp + n * 16 + lr + kk;
        bf[n] = *(const s16x8*)(lds + ((row * 128 + cib * 2 + g * 16) ^ ((row & 7) << 4)));
      }
      #pragma unroll
      for (int m = 0; m < 4; ++m)
        #pragma unroll
        for (int n = 0; n < 2; ++n)
          acc[m][n] = __builtin_amdgcn_mfma_f32_16x16x32_bf16(a[m], bf[n], acc[m][n], 0, 0, 0);
    }
  }

  #pragma unroll
  for (int m = 0; m < 4; ++m) {
    int co0 = m * 16 + g * 4;
    float sc[4], sh[4];
    #pragma unroll
    for (int j = 0; j < 4; ++j) { sc[j] = scs[(co0 + j) * 2]; sh[j] = scs[(co0 + j) * 2 + 1]; }
    #pragma unroll
    for (int n = 0; n < 2; ++n) {
      u16x4 o;
      #pragma unroll
      for (int j = 0; j < 4; ++j) {
        float t = fmaxf(fmaf(acc[m][n][j], sc[j], sh[j]), 0.f);
        float t1 = fmaxf(t, __shfl_xor(t, 1));
        float t2 = fmaxf(t1, __shfl_xor(t1, 2));
        o[j] = f2bf(t2);
      }
      int pp = (l0 + wp + n * 16 + lr) >> 2;
      if ((l & 3) == 0 && pp < 187)
        *(u16x4*)(h3pt + (b * 187 + pp) * 128 + cg0 + co0) = o;
    }
  }
}

// ---------------------------------------------------------------------------
// conv4 MFMA: h3pt -> BN+ReLU -> masked sum over pos -> atomicAdd h4 (fp32)
// block: co64(half) x pos64(third); wave 2x2 of (co32(2m) x pos32(2n))
// K=896, 4 w-chunks of 224
// ---------------------------------------------------------------------------
__global__ __launch_bounds__(256) void k_conv4(
    const unsigned short* __restrict__ h3pt, const unsigned short* __restrict__ w4p,
    const float* __restrict__ cb, const float* __restrict__ bng,
    const float* __restrict__ bnb, float* __restrict__ h4)
{
  __shared__ __align__(16) char lds[72 * 256 + 28672 + 512];
  float* scs = (float*)(lds + 72 * 256 + 28672);
  const int tid = threadIdx.x, b = blockIdx.y;
  const int ch = blockIdx.x & 1, pt = blockIdx.x >> 1;
  const int cg0 = ch * 64, p0 = pt * 64;

  for (int e = tid; e < 1120; e += 256) {  // 70 rows x 16 chunks
    int r = e >> 4, c = e & 15;
    int gr = p0 + r - 3;
    s16x8 v;
    if (gr >= 0 && gr < 187) v = *(const s16x8*)(h3pt + (b * 187 + gr) * 128 + c * 8);
    else for (int i = 0; i < 8; ++i) v[i] = 0;
    *(s16x8*)(lds + ((r * 256 + c * 16) ^ ((r & 7) << 4))) = v;
  }
  if (tid < 64) {
    int co = cg0 + tid;
    float sc = bng[co] * BN_INV;
    scs[tid * 2] = sc;
    scs[tid * 2 + 1] = fmaf(cb[co], sc, bnb[co]);
  }

  const int w = tid >> 6, l = tid & 63, lr = l & 15, g = l >> 4;
  const int co_off = (w & 1) * 32, pos_off = (w >> 1) * 32;
  f32x4 acc[2][2];
  for (int m = 0; m < 2; ++m)
    for (int n = 0; n < 2; ++n)
      for (int i = 0; i < 4; ++i) acc[m][n][i] = 0.f;

  for (int chunk = 0; chunk < 4; ++chunk) {
    __syncthreads();
    for (int e = tid; e < 1792; e += 256) {  // 64co x 28 chunks (K/4)
      int co = e / 28, c = e % 28;
      s16x8 v = *(const s16x8*)(w4p + (cg0 + co) * 896 + chunk * 224 + c * 8);
      *(s16x8*)(lds + 18432 + ((co * 448 + c * 16) ^ ((co & 7) << 4))) = v;
    }
    __syncthreads();
    #pragma unroll
    for (int sl = 0; sl < 7; ++sl) {
      int k0 = chunk * 224 + sl * 32;
      int kk = k0 >> 7, cib = k0 & 127;
      s16x8 a[2], bf[2];
      #pragma unroll
      for (int m = 0; m < 2; ++m) {
        int co = co_off + m * 16 + lr;
        a[m] = *(const s16x8*)(lds + 18432 + ((co * 448 + sl * 64 + g * 16) ^ ((co & 7) << 4)));
      }
      #pragma unroll
      for (int n = 0; n < 2; ++n) {
        int row = pos_off + n * 16 + lr + kk;
        bf[n] = *(const s16x8*)(lds + ((row * 256 + cib * 2 + g * 16) ^ ((row & 7) << 4)));
      }
      #pragma unroll
      for (int m = 0; m < 2; ++m)
        #pragma unroll
        for (int n = 0; n < 2; ++n)
          acc[m][n] = __builtin_amdgcn_mfma_f32_16x16x32_bf16(a[m], bf[n], acc[m][n], 0, 0, 0);
    }
  }

  float psum[2][4];
  for (int m = 0; m < 2; ++m)
    for (int j = 0; j < 4; ++j) psum[m][j] = 0.f;
  #pragma unroll
  for (int m = 0; m < 2; ++m) {
    int col = co_off + m * 16 + g * 4;  // local co base
    #pragma unroll
    for (int n = 0; n < 2; ++n) {
      int pos_g = p0 + pos_off + n * 16 + lr;
      #pragma unroll
      for (int j = 0; j < 4; ++j) {
        float t = fmaxf(fmaf(acc[m][n][j], scs[(col + j) * 2], scs[(col + j) * 2 + 1]), 0.f);
        if (pos_g < 187) psum[m][j] += t;
      }
    }
  }
  #pragma unroll
  for (int m = 0; m < 2; ++m)
    #pragma unroll
    for (int j = 0; j < 4; ++j) {
      float v = psum[m][j];
      v += __shfl_xor(v, 1);
      v += __shfl_xor(v, 2);
      v += __shfl_xor(v, 4);
      v += __shfl_xor(v, 8);
      if (lr == 0)
        atomicAdd(&h4[b * 128 + cg0 + co_off + m * 16 + g * 4 + j], v);
    }
}

// ---------------------------------------------------------------------------
// head: h4 sums -> /187 -> fc+relu -> ang -> pi*tanh -> 8-qubit sim -> out
// ---------------------------------------------------------------------------
__global__ __launch_bounds__(256) void k_head(
    const float* __restrict__ h4, const float* __restrict__ fc_w,
    const float* __restrict__ fc_b, const float* __restrict__ ang_w,
    const float* __restrict__ ang_b, const float* __restrict__ qw,
    const float* __restrict__ h1_w, const float* __restrict__ h1_b,
    const float* __restrict__ h2_w, const float* __restrict__ h2_b,
    float* __restrict__ out)
{
  __shared__ float hvec[128], fvec[128];
  __shared__ float rc[8], rs[8];
  __shared__ float rotm[16][8];
  __shared__ float2 st[256];
  __shared__ float parr[256];
  __shared__ float zv[8];
  __shared__ float hh[64];

  const int tid = threadIdx.x;
  const int b = blockIdx.x;

  if (tid < 128) hvec[tid] = h4[b * 128 + tid] * (1.0f / 187.0f);
  __syncthreads();

  if (tid < 128) {
    float a = fc_b[tid];
    const float* wr = fc_w + tid * 128;
    for (int k = 0; k < 128; ++k) a = fmaf(hvec[k], wr[k], a);
    fvec[tid] = fmaxf(a, 0.f);
  }
  __syncthreads();

  if (tid < 8) {
    float a = ang_b[tid];
    const float* wr = ang_w + tid * 128;
    for (int k = 0; k < 128; ++k) a = fmaf(fvec[k], wr[k], a);
    float ang = PI_F * tanhf(a);
    rc[tid] = cosf(0.5f * ang);
    rs[tid] = sinf(0.5f * ang);
  }
  if (tid >= 32 && tid < 48) {
    int g = tid - 32;
    float phi = qw[g * 3 + 0], th = qw[g * 3 + 1], om = qw[g * 3 + 2];
    float cm = cosf(0.5f * th), sm = sinf(0.5f * th);
    float a = 0.5f * (phi + om), bb = 0.5f * (phi - om);
    float ca = cosf(a), sa = sinf(a), cbb = cosf(bb), sbb = sinf(bb);
    rotm[g][0] =  cm * ca;  rotm[g][1] = -cm * sa;
    rotm[g][2] = -sm * cbb; rotm[g][3] = -sm * sbb;
    rotm[g][4] =  sm * cbb; rotm[g][5] = -sm * sbb;
    rotm[g][6] =  cm * ca;  rotm[g][7] =  cm * sa;
  }
  st[tid] = make_float2(tid == 0 ? 1.f : 0.f, 0.f);
  __syncthreads();

  for (int w = 0; w < 8; ++w) {
    if (tid < 128) {
      int bit = 7 - w;
      int i0 = ((tid >> bit) << (bit + 1)) | (tid & ((1 << bit) - 1));
      int i1 = i0 | (1 << bit);
      float c = rc[w], s = rs[w];
      float2 a0 = st[i0], a1 = st[i1];
      st[i0] = make_float2(c * a0.x - s * a1.x, c * a0.y - s * a1.y);
      st[i1] = make_float2(s * a0.x + c * a1.x, s * a0.y + c * a1.y);
    }
    __syncthreads();
  }

  for (int lay = 0; lay < 2; ++lay) {
    for (int w = 0; w < 8; ++w) {
      if (tid < 128) {
        int g = lay * 8 + w;
        int bit = 7 - w;
        int i0 = ((tid >> bit) << (bit + 1)) | (tid & ((1 << bit) - 1));
        int i1 = i0 | (1 << bit);
        float2 a0 = st[i0], a1 = st[i1];
        float2 n0, n1;
        n0.x = rotm[g][0] * a0.x - rotm[g][1] * a0.y + rotm[g][2] * a1.x - rotm[g][3] * a1.y;
        n0.y = rotm[g][0] * a0.y + rotm[g][1] * a0.x + rotm[g][2] * a1.y + rotm[g][3] * a1.x;
        n1.x = rotm[g][4] * a0.x - rotm[g][5] * a0.y + rotm[g][6] * a1.x - rotm[g][7] * a1.y;
        n1.y = rotm[g][4] * a0.y + rotm[g][5] * a0.x + rotm[g][6] * a1.y + rotm[g][7] * a1.x;
        st[i0] = n0;
        st[i1] = n1;
      }
      __syncthreads();
    }
    int r = (lay % 7) + 1;
    for (int i = 0; i < 8; ++i) {
      int c = i, t = (i + r) & 7;
      int cmask = 1 << (7 - c), tmask = 1 << (7 - t);
      int src = (tid & cmask) ? (tid ^ tmask) : tid;
      float2 v = st[src];
      __syncthreads();
      st[tid] = v;
      __syncthreads();
    }
  }

  parr[tid] = st[tid].x * st[tid].x + st[tid].y * st[tid].y;
  __syncthreads();
  if (tid < 8) {
    int bit = 7 - tid;
    float z = 0.f;
    for (int i = 0; i < 256; ++i)
      z += (i & (1 << bit)) ? -parr[i] : parr[i];
    zv[tid] = z;
  }
  __syncthreads();
  if (tid < 64) {
    float a = h1_b[tid];
    #pragma unroll
    for (int k = 0; k < 8; ++k) a = fmaf(zv[k], h1_w[tid * 8 + k], a);
    hh[tid] = fmaxf(a, 0.f);
  }
  __syncthreads();
  if (tid < 5) {
    float a = h2_b[tid];
    for (int j = 0; j < 64; ++j) a = fmaf(hh[j], h2_w[tid * 64 + j], a);
    out[b * 5 + tid] = a;
  }
}

// ---------------------------------------------------------------------------
extern "C" void kernel_launch(void* const* d_in, const int* in_sizes, int n_in,
                              void* d_out, int out_size, void* d_ws, size_t ws_size,
                              hipStream_t stream) {
  (void)in_sizes; (void)n_in; (void)out_size; (void)ws_size;
  const float* x    = (const float*)d_in[0];
  const float* c1w  = (const float*)d_in[1];
  const float* c1b  = (const float*)d_in[2];
  const float* b1g  = (const float*)d_in[3];
  const float* b1b  = (const float*)d_in[4];
  const float* c2w  = (const float*)d_in[5];
  const float* c2b  = (const float*)d_in[6];
  const float* b2g  = (const float*)d_in[7];
  const float* b2b  = (const float*)d_in[8];
  const float* c3w  = (const float*)d_in[9];
  const float* c3b  = (const float*)d_in[10];
  const float* b3g  = (const float*)d_in[11];
  const float* b3b  = (const float*)d_in[12];
  const float* c4w  = (const float*)d_in[13];
  const float* c4b  = (const float*)d_in[14];
  const float* b4g  = (const float*)d_in[15];
  const float* b4b  = (const float*)d_in[16];
  const float* fcw  = (const float*)d_in[17];
  const float* fcb  = (const float*)d_in[18];
  const float* angw = (const float*)d_in[19];
  const float* angb = (const float*)d_in[20];
  const float* qw   = (const float*)d_in[21];
  const float* h1w  = (const float*)d_in[22];
  const float* h1b  = (const float*)d_in[23];
  const float* h2w  = (const float*)d_in[24];
  const float* h2b  = (const float*)d_in[25];

  char* wsb = (char*)d_ws;
  unsigned short* w1p  = (unsigned short*)(wsb + 0);        // 4096 B
  unsigned short* w2p  = (unsigned short*)(wsb + 4096);     // 28672 B
  unsigned short* w3p  = (unsigned short*)(wsb + 32768);    // 114688 B
  unsigned short* w4p  = (unsigned short*)(wsb + 147456);   // 229376 B
  float*          h4   = (float*)(wsb + 393216);            // 131072 B
  unsigned short* h1t  = (unsigned short*)(wsb + 1048576);  // 49.15 MB
  unsigned short* h2pt = (unsigned short*)(wsb + 52428800); // 24.58 MB
  unsigned short* h3pt = (unsigned short*)(wsb + 79691776); // 12.25 MB

  k_pack<<<dim3(864), 256, 0, stream>>>(c1w, c2w, c3w, c4w, w1p, w2p, w3p, w4p, h4);
  k_conv1<<<dim3(6, 256),  256, 0, stream>>>(x, w1p, c1b, b1g, b1b, h1t);
  k_conv2<<<dim3(12, 256), 256, 0, stream>>>(h1t, w2p, c2b, b2g, b2b, h2pt);
  k_conv3<<<dim3(12, 256), 256, 0, stream>>>(h2pt, w3p, c3b, b3g, b3b, h3pt);
  k_conv4<<<dim3(6, 256),  256, 0, stream>>>(h3pt, w4p, c4b, b4g, b4b, h4);
  k_head<<<dim3(256), 256, 0, stream>>>(h4, fcw, fcb, angw, angb, qw,
                                        h1w, h1b, h2w, h2b, (float*)d_out);
}